// Round 3
// baseline (115.054 us; speedup 1.0000x reference)
//
#include <hip/hip_runtime.h>

// (B,H,W,D) = (4,128,128,128) fp32, row-major, D innermost.
// R = -2*exp(-2*Phi) * (lap + 2*|grad Phi|^2), Phi = pos - lam*neg, edge-clamped, h=1.
//
// Thread = one float4 along D (32 vec per D-row). A 64-lane wave covers exactly
// 2 contiguous D-rows, so z-direction edge scalars come from lane+-1 via shfl
// instead of extra global loads (row-crossing lanes are clamped anyway).

#define NVEC (4 * 128 * 128 * 32)   // total float4 elements

// Native clang vector type — required by __builtin_nontemporal_store
// (HIP's float4 is a class and is rejected by the builtin).
typedef float vfloat4 __attribute__((ext_vector_type(4)));

__global__ __launch_bounds__(256) void conformal_kernel(
    const float* __restrict__ pos, const float* __restrict__ neg,
    const float* __restrict__ lamp, float* __restrict__ out)
{
    const float lam = lamp[0];
    const int vid = blockIdx.x * blockDim.x + threadIdx.x;  // float4 index

    const int dvec = vid & 31;          // float4 index along D (32 per row)
    const int w    = (vid >> 5)  & 127;
    const int h    = (vid >> 12) & 127;

    const vfloat4* posv = (const vfloat4*)pos;
    const vfloat4* negv = (const vfloat4*)neg;

    // Edge clamp: out-of-range neighbor folds back to center.
    const int i_yp = (w < 127) ? vid + 32   : vid;
    const int i_ym = (w > 0)   ? vid - 32   : vid;
    const int i_xp = (h < 127) ? vid + 4096 : vid;
    const int i_xm = (h > 0)   ? vid - 4096 : vid;

    vfloat4 p_c  = posv[vid],  n_c  = negv[vid];
    vfloat4 p_yp = posv[i_yp], n_yp = negv[i_yp];
    vfloat4 p_ym = posv[i_ym], n_ym = negv[i_ym];
    vfloat4 p_xp = posv[i_xp], n_xp = negv[i_xp];
    vfloat4 p_xm = posv[i_xm], n_xm = negv[i_xm];

    // Phi at center
    const vfloat4 cphi = p_c - lam * n_c;
    const float c0 = cphi.x, c1 = cphi.y, c2 = cphi.z, c3 = cphi.w;

    // z-edge neighbors via cross-lane shuffle (wave=64 = 2 full D-rows).
    // left  = Phi[d-1] for element 0  = previous lane's c3
    // right = Phi[d+1] for element 3  = next lane's c0
    const float from_up   = __shfl_up(c3, 1);    // garbage at lane 0 — clamped below
    const float from_down = __shfl_down(c0, 1);  // garbage at lane 63 — clamped below
    const float left  = (dvec > 0)  ? from_up   : c0;  // d=-1 clamps to d=0
    const float right = (dvec < 31) ? from_down : c3;  // d=128 clamps to d=127

    const vfloat4 xp = p_xp - lam * n_xp;
    const vfloat4 xm = p_xm - lam * n_xm;
    const vfloat4 yp = p_yp - lam * n_yp;
    const vfloat4 ym = p_ym - lam * n_ym;

    const float cc[4]  = { c0, c1, c2, c3 };
    const float zl[4]  = { left, c0, c1, c2 };   // Phi at d-1
    const float zr[4]  = { c1, c2, c3, right };  // Phi at d+1
    const float xpv[4] = { xp.x, xp.y, xp.z, xp.w };
    const float xmv[4] = { xm.x, xm.y, xm.z, xm.w };
    const float ypv[4] = { yp.x, yp.y, yp.z, yp.w };
    const float ymv[4] = { ym.x, ym.y, ym.z, ym.w };

    vfloat4 o;
#pragma unroll
    for (int j = 0; j < 4; ++j) {
        const float gx = (xpv[j] - xmv[j]) * 0.5f;
        const float gy = (ypv[j] - ymv[j]) * 0.5f;
        const float gz = (zr[j]  - zl[j])  * 0.5f;
        const float grad_sq = gx * gx + gy * gy + gz * gz;
        const float lap = xpv[j] + xmv[j] + ypv[j] + ymv[j] + zl[j] + zr[j]
                          - 6.0f * cc[j];
        o[j] = -2.0f * __expf(-2.0f * cc[j]) * (lap + 2.0f * grad_sq);
    }

    // Output is never re-read: nontemporal store keeps L2/L3 for the inputs.
    __builtin_nontemporal_store(o, ((vfloat4*)out) + vid);
}

extern "C" void kernel_launch(void* const* d_in, const int* in_sizes, int n_in,
                              void* d_out, int out_size, void* d_ws, size_t ws_size,
                              hipStream_t stream) {
    const float* pos = (const float*)d_in[0];
    const float* neg = (const float*)d_in[1];
    const float* lam = (const float*)d_in[2];
    float* out = (float*)d_out;

    const int threads = 256;
    const int blocks  = NVEC / threads;  // 8192
    conformal_kernel<<<blocks, threads, 0, stream>>>(pos, neg, lam, out);
}

// Round 4
// 106.107 us; speedup vs baseline: 1.0843x; 1.0843x over previous
//
#include <hip/hip_runtime.h>

// (B,H,W,D) = (4,128,128,128) fp32, row-major, D innermost.
// R = -2*exp(-2*Phi) * (lap + 2*|grad Phi|^2), Phi = pos - lam*neg, edge-clamped, h=1.
//
// Thread = one float4 along D (32 vec per D-row). A 64-lane wave covers exactly
// 2 contiguous D-rows, so z-direction edge scalars come from lane+-1 via shfl
// instead of extra global loads (row-crossing lanes are clamped anyway).
//
// R3 post-mortem: nontemporal store regressed dur_us 107.8->115.1 (suspected
// L2/L3 no-allocate write-through penalty). This round: shfl kept, plain store.

#define NVEC (4 * 128 * 128 * 32)   // total float4 elements

typedef float vfloat4 __attribute__((ext_vector_type(4)));

__global__ __launch_bounds__(256) void conformal_kernel(
    const float* __restrict__ pos, const float* __restrict__ neg,
    const float* __restrict__ lamp, float* __restrict__ out)
{
    const float lam = lamp[0];
    const int vid = blockIdx.x * blockDim.x + threadIdx.x;  // float4 index

    const int dvec = vid & 31;          // float4 index along D (32 per row)
    const int w    = (vid >> 5)  & 127;
    const int h    = (vid >> 12) & 127;

    const vfloat4* posv = (const vfloat4*)pos;
    const vfloat4* negv = (const vfloat4*)neg;

    // Edge clamp: out-of-range neighbor folds back to center.
    const int i_yp = (w < 127) ? vid + 32   : vid;
    const int i_ym = (w > 0)   ? vid - 32   : vid;
    const int i_xp = (h < 127) ? vid + 4096 : vid;
    const int i_xm = (h > 0)   ? vid - 4096 : vid;

    vfloat4 p_c  = posv[vid],  n_c  = negv[vid];
    vfloat4 p_yp = posv[i_yp], n_yp = negv[i_yp];
    vfloat4 p_ym = posv[i_ym], n_ym = negv[i_ym];
    vfloat4 p_xp = posv[i_xp], n_xp = negv[i_xp];
    vfloat4 p_xm = posv[i_xm], n_xm = negv[i_xm];

    // Phi at center
    const vfloat4 cphi = p_c - lam * n_c;
    const float c0 = cphi.x, c1 = cphi.y, c2 = cphi.z, c3 = cphi.w;

    // z-edge neighbors via cross-lane shuffle (wave=64 = 2 full D-rows).
    // left  = Phi[d-1] for element 0  = previous lane's c3
    // right = Phi[d+1] for element 3  = next lane's c0
    const float from_up   = __shfl_up(c3, 1);    // garbage at lane 0 — clamped below
    const float from_down = __shfl_down(c0, 1);  // garbage at lane 63 — clamped below
    const float left  = (dvec > 0)  ? from_up   : c0;  // d=-1 clamps to d=0
    const float right = (dvec < 31) ? from_down : c3;  // d=128 clamps to d=127

    const vfloat4 xp = p_xp - lam * n_xp;
    const vfloat4 xm = p_xm - lam * n_xm;
    const vfloat4 yp = p_yp - lam * n_yp;
    const vfloat4 ym = p_ym - lam * n_ym;

    const float cc[4]  = { c0, c1, c2, c3 };
    const float zl[4]  = { left, c0, c1, c2 };   // Phi at d-1
    const float zr[4]  = { c1, c2, c3, right };  // Phi at d+1
    const float xpv[4] = { xp.x, xp.y, xp.z, xp.w };
    const float xmv[4] = { xm.x, xm.y, xm.z, xm.w };
    const float ypv[4] = { yp.x, yp.y, yp.z, yp.w };
    const float ymv[4] = { ym.x, ym.y, ym.z, ym.w };

    vfloat4 o;
#pragma unroll
    for (int j = 0; j < 4; ++j) {
        const float gx = (xpv[j] - xmv[j]) * 0.5f;
        const float gy = (ypv[j] - ymv[j]) * 0.5f;
        const float gz = (zr[j]  - zl[j])  * 0.5f;
        const float grad_sq = gx * gx + gy * gy + gz * gz;
        const float lap = xpv[j] + xmv[j] + ypv[j] + ymv[j] + zl[j] + zr[j]
                          - 6.0f * cc[j];
        o[j] = -2.0f * __expf(-2.0f * cc[j]) * (lap + 2.0f * grad_sq);
    }

    ((vfloat4*)out)[vid] = o;  // plain cached store (nt store regressed in R3)
}

extern "C" void kernel_launch(void* const* d_in, const int* in_sizes, int n_in,
                              void* d_out, int out_size, void* d_ws, size_t ws_size,
                              hipStream_t stream) {
    const float* pos = (const float*)d_in[0];
    const float* neg = (const float*)d_in[1];
    const float* lam = (const float*)d_in[2];
    float* out = (float*)d_out;

    const int threads = 256;
    const int blocks  = NVEC / threads;  // 8192
    conformal_kernel<<<blocks, threads, 0, stream>>>(pos, neg, lam, out);
}